// Round 11
// baseline (4491.747 us; speedup 1.0000x reference)
//
#include <hip/hip_runtime.h>
#include <math.h>

constexpr int NY_ = 320, NX_ = 320, NT_ = 160, SHOTS_ = 2, NSRC_ = 8, NREC_ = 96;
constexpr float DT_  = 4.0e-4f;
constexpr float C1_  = 9.0f / 8.0f;
constexpr float C2_  = -1.0f / 24.0f;
constexpr float IDH_ = 0.25f;           // 1/DH, exact
constexpr int NSTRIP_ = 40;             // 8-row strips per shot
constexpr int NBLK_   = SHOTS_ * NSTRIP_;
// Per-strip publish slots (12 rows x 320 floats, single-buffered — overwrite at
// t+1 is ordered behind the remote reader's phase-t flag, which the writer polls):
//  vel:    0=vy r0  1=vx r0  2=vy r0+1  3=vx r0+6  4=vy r0+7  5=vx r0+7
//  stress: 6=syy r0 7=sxy r0 8=sxy r0+1 9=syy r0+6 10=syy r0+7 11=sxy r0+7
// Flags[sj*16+i]: 0=VB0 1=VB1 2=VT6 3=VT7 4=SB0 5=SB1 6=ST6 7=ST7 (value = phases done)
constexpr int FLG_OFF_ = NBLK_ * 12 * NX_;
constexpr int REC_OFF_ = FLG_OFF_ + NBLK_ * 16;
constexpr int WS_WORDS_ = REC_OFF_ + SHOTS_ * NREC_ * NT_ + 64;

// ---- all cross-block traffic: agent-scope relaxed atomics -> sc0 sc1 (IF).
// Single path only — the r10 same-XCD plain-store path deadlocked (dirty L2
// lines not visible to sc0 loads before writeback). Verified r3-r9.
__device__ __forceinline__ float cld(const float* p) {
    return __hip_atomic_load(p, __ATOMIC_RELAXED, __HIP_MEMORY_SCOPE_AGENT);
}
__device__ __forceinline__ void cst(float* p, float v) {
    __hip_atomic_store(p, v, __ATOMIC_RELAXED, __HIP_MEMORY_SCOPE_AGENT);
}
__device__ __forceinline__ unsigned cldu(const unsigned* p) {
    return __hip_atomic_load(p, __ATOMIC_RELAXED, __HIP_MEMORY_SCOPE_AGENT);
}
__device__ __forceinline__ void cstu(unsigned* p, unsigned v) {
    __hip_atomic_store(p, v, __ATOMIC_RELAXED, __HIP_MEMORY_SCOPE_AGENT);
}
// ---- LDS progress flags (workgroup-scope acquire/release; r9-verified)
__device__ __forceinline__ void lwait(const unsigned* f, unsigned tgt) {
    while (__hip_atomic_load(f, __ATOMIC_ACQUIRE, __HIP_MEMORY_SCOPE_WORKGROUP) < tgt) {}
}
__device__ __forceinline__ void lpost(unsigned* f, unsigned v) {
    __hip_atomic_store(f, v, __ATOMIC_RELEASE, __HIP_MEMORY_SCOPE_WORKGROUP);
}
// ---- global flag polls (whole edge wave spins on 1-2 flags)
__device__ __forceinline__ void gpoll1(const unsigned* a, unsigned tgt) {
    while (cldu(a) < tgt) __builtin_amdgcn_s_sleep(1);
    asm volatile("" ::: "memory");
}
__device__ __forceinline__ void gpoll2(const unsigned* a, const unsigned* b, unsigned tgt) {
    while (cldu(a) < tgt || cldu(b) < tgt) __builtin_amdgcn_s_sleep(1);
    asm volatile("" ::: "memory");
}
// register x-tap via wave shuffle (r5-r9 verified; cells 64-col interleaved)
__device__ __forceinline__ float shtap(float cur, float adj, int lane, int dx) {
    int idx = (lane + dx) & 63;
    float a = __shfl(cur, idx, 64);
    float b = __shfl(adj, idx, 64);
    return ((unsigned)(lane + dx) < 64u) ? a : b;
}

__global__ void init_kernel(float* __restrict__ ws) {
    for (int i = blockIdx.x * 256 + threadIdx.x; i < WS_WORDS_; i += gridDim.x * 256)
        ws[i] = 0.0f;
}

__global__ __launch_bounds__(512, 2)
void elastic_kernel(const float* __restrict__ lamb, const float* __restrict__ mu,
                    const float* __restrict__ buoy, const float* __restrict__ amps,
                    const int* __restrict__ src_loc, const int* __restrict__ rec_loc,
                    float* __restrict__ out, float* __restrict__ ws)
{
    __shared__ float Lvy[8][NX_], Lvx[8][NX_], Lsyy[8][NX_], Lsxy[8][NX_];
    __shared__ unsigned vF[8], sF[8];

    const int tid = threadIdx.x, lane = tid & 63, w = tid >> 6;   // wave = row
    const int bid = blockIdx.x, s = bid / NSTRIP_, j = bid % NSTRIP_;
    const int r0 = j * 8, gy = r0 + w, sj = bid;
    const int wm1 = (w >= 1) ? w - 1 : 0, wm2 = (w >= 2) ? w - 2 : 0;
    const int wp1 = (w <= 6) ? w + 1 : 7, wp2 = (w <= 5) ? w + 2 : 7;
    float* SL = ws;                                   // slots [sj][12][NX_]
    unsigned* FL = (unsigned*)(ws + FLG_OFF_);        // flags [sj][16]
    float* recbase = ws + REC_OFF_;

    // --- loop invariants (double PML; formulas verbatim r6/r9, absmax 2.5e-29) ---
    const double d0 = 3.0 * 1600.0 * log(1000.0) / (2.0 * 20.0 * 4.0);
    double py = 0.0;
    if (gy < 20)             { double u = (20.0 - gy) / 20.0;           py = u * u; }
    else if (gy >= NY_ - 20) { double u = (gy - (NY_ - 1 - 20)) / 20.0; py = u * u; }
    const float by = (float)exp(-d0 * py * 4.0e-4);
    const float bym1 = by - 1.0f;

    float bx[5], bxm1[5], mk[5], la[5], muv[5], bu[5], l2m[5];
    #pragma unroll
    for (int k = 0; k < 5; ++k) {
        int c = 64 * k + lane;
        double px = 0.0;
        if (c < 20)             { double u = (20.0 - c) / 20.0;           px = u * u; }
        else if (c >= NX_ - 20) { double u = (c - (NX_ - 1 - 20)) / 20.0; px = u * u; }
        bx[k] = (float)exp(-d0 * px * 4.0e-4);
        bxm1[k] = bx[k] - 1.0f;
        mk[k] = (gy < 2 || gy >= NY_ - 2 || c < 2 || c >= NX_ - 2) ? 0.0f : 1.0f;
        la[k]  = lamb[gy * NX_ + c];
        muv[k] = mu[gy * NX_ + c];
        bu[k]  = buoy[gy * NX_ + c];
        l2m[k] = la[k] + 2.0f * muv[k];
    }
    unsigned long long sm = 0ull;
    for (int js = 0; js < NSRC_; ++js) {
        int sy = src_loc[(s * NSRC_ + js) * 2 + 0];
        int sxc = src_loc[(s * NSRC_ + js) * 2 + 1];
        if (sy == gy && (sxc & 63) == lane) sm |= 1ull << (8 * (sxc >> 6) + js);
    }
    int nrec = 0, recid[8], reck[8];
    for (int r = 0; r < NREC_; ++r) {
        int ry = rec_loc[(s * NREC_ + r) * 2 + 0];
        int rx = rec_loc[(s * NREC_ + r) * 2 + 1];
        if (ry == gy && (rx & 63) == lane && nrec < 8) { recid[nrec] = r; reck[nrec] = rx >> 6; ++nrec; }
    }

    for (int i = tid; i < 8 * NX_; i += 512) {
        ((float*)Lvy)[i] = 0.f; ((float*)Lvx)[i] = 0.f;
        ((float*)Lsyy)[i] = 0.f; ((float*)Lsxy)[i] = 0.f;
    }
    if (tid < 8) { vF[tid] = 0u; sF[tid] = 0u; }
    __syncthreads();   // only block barrier in the kernel

    float vy[5] = {}, vx[5] = {}, syy[5] = {}, sxy[5] = {}, sxx[5] = {};
    float msyyy[5] = {}, msxyy[5] = {}, msxyx[5] = {}, msxxx[5] = {};
    float mvyy[5] = {}, mvyx[5] = {}, mvxy[5] = {}, mvxx[5] = {};

    const bool hasB = (j > 0), hasT = (j < NSTRIP_ - 1);

    for (int t = 0; t < NT_; ++t) {
        const unsigned ut = (unsigned)t;

        // ================= VELOCITY(t): needs stress(t-1) =================
        float hA[5] = {}, hB[5] = {}, hC[5] = {};
        if (w == 0 && hasB) {
            gpoll2(&FL[(sj - 1) * 16 + 6], &FL[(sj - 1) * 16 + 7], ut);
            const float* B = SL + (sj - 1) * 12 * NX_;
            #pragma unroll
            for (int k = 0; k < 5; ++k) { int c = 64 * k + lane;
                hA[k] = cld(B + 10 * NX_ + c);   // syy r0-1
                hB[k] = cld(B + 9  * NX_ + c);   // syy r0-2
                hC[k] = cld(B + 11 * NX_ + c); } // sxy r0-1
        } else if (w == 1 && hasB) {
            gpoll1(&FL[(sj - 1) * 16 + 7], ut);
            const float* B = SL + (sj - 1) * 12 * NX_;
            #pragma unroll
            for (int k = 0; k < 5; ++k) hA[k] = cld(B + 10 * NX_ + 64 * k + lane);  // syy r0-1
        } else if (w == 6 && hasT) {
            gpoll1(&FL[(sj + 1) * 16 + 4], ut);
            const float* B = SL + (sj + 1) * 12 * NX_;
            #pragma unroll
            for (int k = 0; k < 5; ++k) hA[k] = cld(B + 7 * NX_ + 64 * k + lane);   // sxy r0+8
        } else if (w == 7 && hasT) {
            gpoll2(&FL[(sj + 1) * 16 + 4], &FL[(sj + 1) * 16 + 5], ut);
            const float* B = SL + (sj + 1) * 12 * NX_;
            #pragma unroll
            for (int k = 0; k < 5; ++k) { int c = 64 * k + lane;
                hA[k] = cld(B + 6 * NX_ + c);    // syy r0+8
                hB[k] = cld(B + 7 * NX_ + c);    // sxy r0+8
                hC[k] = cld(B + 8 * NX_ + c); }  // sxy r0+9
        }
        if (w >= 2) lwait(&sF[w - 2], ut);
        if (w >= 1) lwait(&sF[w - 1], ut);
        if (w <= 6) lwait(&sF[w + 1], ut);
        if (w <= 5) lwait(&sF[w + 2], ut);

        #pragma unroll
        for (int k = 0; k < 5; ++k) {
            const int c = 64 * k + lane;
            const float sxyP = (k < 4) ? sxy[k + 1] : 0.0f;
            const float sxyM = (k > 0) ? sxy[k - 1] : 0.0f;
            const float sxxP = (k < 4) ? sxx[k + 1] : 0.0f;
            const float sxxM = (k > 0) ? sxx[k - 1] : 0.0f;
            const float syy_m1 = (w >= 1) ? Lsyy[wm1][c] : hA[k];
            const float syy_p1 = (w <= 6) ? Lsyy[wp1][c] : hA[k];
            const float syy_m2 = (w >= 2) ? Lsyy[wm2][c] : ((w == 1) ? hA[k] : hB[k]);
            const float sxy_m1 = (w >= 1) ? Lsxy[wm1][c] : hC[k];
            const float sxy_p1 = (w <= 6) ? Lsxy[wp1][c] : hB[k];
            const float sxy_p2 = (w <= 5) ? Lsxy[wp2][c] : ((w == 6) ? hA[k] : hC[k]);
            float d, ay, ax;
            d = (C1_ * (syy[k] - syy_m1) + C2_ * (syy_p1 - syy_m2)) * IDH_;
            msyyy[k] = by * msyyy[k] + bym1 * d;
            ay = d + msyyy[k];
            d = (C1_ * (shtap(sxy[k], sxyP, lane, 1) - sxy[k])
               + C2_ * (shtap(sxy[k], sxyP, lane, 2) - shtap(sxy[k], sxyM, lane, -1))) * IDH_;
            msxyx[k] = bx[k] * msxyx[k] + bxm1[k] * d;
            ay = ay + d + msxyx[k];
            vy[k] = vy[k] + DT_ * bu[k] * ay;
            d = (C1_ * (sxx[k] - shtap(sxx[k], sxxM, lane, -1))
               + C2_ * (shtap(sxx[k], sxxP, lane, 1) - shtap(sxx[k], sxxM, lane, -2))) * IDH_;
            msxxx[k] = bx[k] * msxxx[k] + bxm1[k] * d;
            ax = d + msxxx[k];
            d = (C1_ * (sxy_p1 - sxy[k]) + C2_ * (sxy_p2 - sxy_m1)) * IDH_;
            msxyy[k] = by * msxyy[k] + bym1 * d;
            ax = ax + d + msxyy[k];
            vx[k] = vx[k] + DT_ * bu[k] * ax;
            unsigned m = (unsigned)(sm >> (8 * k)) & 0xFFu;
            if (m) {
                for (int js = 0; js < NSRC_; ++js)
                    if (m & (1u << js)) vy[k] += DT_ * amps[(s * NSRC_ + js) * NT_ + t] * bu[k];
            }
            vy[k] *= mk[k]; vx[k] *= mk[k];
            Lvy[w][c] = vy[k]; Lvx[w][c] = vx[k];
        }
        lpost(&vF[w], ut + 1u);
        for (int i = 0; i < nrec; ++i)
            recbase[(s * NREC_ + recid[i]) * NT_ + t] = vy[reck[i]];

        if (w == 0 && hasB) {
            float* P = SL + sj * 12 * NX_;
            #pragma unroll
            for (int k = 0; k < 5; ++k) { int c = 64 * k + lane;
                cst(P + 0 * NX_ + c, vy[k]); cst(P + 1 * NX_ + c, vx[k]); }
            asm volatile("s_waitcnt vmcnt(0)" ::: "memory");
            cstu(&FL[sj * 16 + 0], ut + 1u);
        } else if (w == 1 && hasB) {
            float* P = SL + sj * 12 * NX_;
            #pragma unroll
            for (int k = 0; k < 5; ++k) cst(P + 2 * NX_ + 64 * k + lane, vy[k]);
            asm volatile("s_waitcnt vmcnt(0)" ::: "memory");
            cstu(&FL[sj * 16 + 1], ut + 1u);
        } else if (w == 6 && hasT) {
            float* P = SL + sj * 12 * NX_;
            #pragma unroll
            for (int k = 0; k < 5; ++k) cst(P + 3 * NX_ + 64 * k + lane, vx[k]);
            asm volatile("s_waitcnt vmcnt(0)" ::: "memory");
            cstu(&FL[sj * 16 + 2], ut + 1u);
        } else if (w == 7 && hasT) {
            float* P = SL + sj * 12 * NX_;
            #pragma unroll
            for (int k = 0; k < 5; ++k) { int c = 64 * k + lane;
                cst(P + 4 * NX_ + c, vy[k]); cst(P + 5 * NX_ + c, vx[k]); }
            asm volatile("s_waitcnt vmcnt(0)" ::: "memory");
            cstu(&FL[sj * 16 + 3], ut + 1u);
        }

        // ================= STRESS(t): needs velocity(t) =================
        #pragma unroll
        for (int k = 0; k < 5; ++k) { hA[k] = 0.f; hB[k] = 0.f; hC[k] = 0.f; }
        if (w == 0 && hasB) {
            gpoll2(&FL[(sj - 1) * 16 + 2], &FL[(sj - 1) * 16 + 3], ut + 1u);
            const float* B = SL + (sj - 1) * 12 * NX_;
            #pragma unroll
            for (int k = 0; k < 5; ++k) { int c = 64 * k + lane;
                hA[k] = cld(B + 4 * NX_ + c);    // vy r0-1
                hB[k] = cld(B + 5 * NX_ + c);    // vx r0-1
                hC[k] = cld(B + 3 * NX_ + c); }  // vx r0-2
        } else if (w == 1 && hasB) {
            gpoll1(&FL[(sj - 1) * 16 + 3], ut + 1u);
            const float* B = SL + (sj - 1) * 12 * NX_;
            #pragma unroll
            for (int k = 0; k < 5; ++k) hA[k] = cld(B + 5 * NX_ + 64 * k + lane);   // vx r0-1
        } else if (w == 6 && hasT) {
            gpoll1(&FL[(sj + 1) * 16 + 0], ut + 1u);
            const float* B = SL + (sj + 1) * 12 * NX_;
            #pragma unroll
            for (int k = 0; k < 5; ++k) hA[k] = cld(B + 0 * NX_ + 64 * k + lane);   // vy r0+8
        } else if (w == 7 && hasT) {
            gpoll2(&FL[(sj + 1) * 16 + 0], &FL[(sj + 1) * 16 + 1], ut + 1u);
            const float* B = SL + (sj + 1) * 12 * NX_;
            #pragma unroll
            for (int k = 0; k < 5; ++k) { int c = 64 * k + lane;
                hA[k] = cld(B + 0 * NX_ + c);    // vy r0+8
                hB[k] = cld(B + 2 * NX_ + c);    // vy r0+9
                hC[k] = cld(B + 1 * NX_ + c); }  // vx r0+8
        }
        if (w >= 2) lwait(&vF[w - 2], ut + 1u);
        if (w >= 1) lwait(&vF[w - 1], ut + 1u);
        if (w <= 6) lwait(&vF[w + 1], ut + 1u);
        if (w <= 5) lwait(&vF[w + 2], ut + 1u);

        #pragma unroll
        for (int k = 0; k < 5; ++k) {
            const int c = 64 * k + lane;
            const float vyP = (k < 4) ? vy[k + 1] : 0.0f;
            const float vyM = (k > 0) ? vy[k - 1] : 0.0f;
            const float vxP = (k < 4) ? vx[k + 1] : 0.0f;
            const float vxM = (k > 0) ? vx[k - 1] : 0.0f;
            const float vy_p1 = (w <= 6) ? Lvy[wp1][c] : hA[k];
            const float vy_p2 = (w <= 5) ? Lvy[wp2][c] : ((w == 6) ? hA[k] : hB[k]);
            const float vy_m1 = (w >= 1) ? Lvy[wm1][c] : hA[k];
            const float vx_m1 = (w >= 1) ? Lvx[wm1][c] : hB[k];
            const float vx_m2 = (w >= 2) ? Lvx[wm2][c] : ((w == 1) ? hA[k] : hC[k]);
            const float vx_p1 = (w <= 6) ? Lvx[wp1][c] : hC[k];
            float d, e1, e2, g;
            d = (C1_ * (vy_p1 - vy[k]) + C2_ * (vy_p2 - vy_m1)) * IDH_;
            mvyy[k] = by * mvyy[k] + bym1 * d;
            e1 = d + mvyy[k];
            d = (C1_ * (vx[k] - shtap(vx[k], vxM, lane, -1))
               + C2_ * (shtap(vx[k], vxP, lane, 1) - shtap(vx[k], vxM, lane, -2))) * IDH_;
            mvxx[k] = bx[k] * mvxx[k] + bxm1[k] * d;
            e2 = d + mvxx[k];
            syy[k] = (syy[k] + DT_ * (l2m[k] * e1 + la[k] * e2)) * mk[k];
            sxx[k] = (sxx[k] + DT_ * (l2m[k] * e2 + la[k] * e1)) * mk[k];
            d = (C1_ * (shtap(vy[k], vyP, lane, 1) - vy[k])
               + C2_ * (shtap(vy[k], vyP, lane, 2) - shtap(vy[k], vyM, lane, -1))) * IDH_;
            mvyx[k] = bx[k] * mvyx[k] + bxm1[k] * d;
            g = d + mvyx[k];
            d = (C1_ * (vx[k] - vx_m1) + C2_ * (vx_p1 - vx_m2)) * IDH_;
            mvxy[k] = by * mvxy[k] + bym1 * d;
            g = g + d + mvxy[k];
            sxy[k] = (sxy[k] + DT_ * muv[k] * g) * mk[k];
            Lsyy[w][c] = syy[k]; Lsxy[w][c] = sxy[k];
        }
        lpost(&sF[w], ut + 1u);

        if (w == 0 && hasB) {
            float* P = SL + sj * 12 * NX_;
            #pragma unroll
            for (int k = 0; k < 5; ++k) { int c = 64 * k + lane;
                cst(P + 6 * NX_ + c, syy[k]); cst(P + 7 * NX_ + c, sxy[k]); }
            asm volatile("s_waitcnt vmcnt(0)" ::: "memory");
            cstu(&FL[sj * 16 + 4], ut + 1u);
        } else if (w == 1 && hasB) {
            float* P = SL + sj * 12 * NX_;
            #pragma unroll
            for (int k = 0; k < 5; ++k) cst(P + 8 * NX_ + 64 * k + lane, sxy[k]);
            asm volatile("s_waitcnt vmcnt(0)" ::: "memory");
            cstu(&FL[sj * 16 + 5], ut + 1u);
        } else if (w == 6 && hasT) {
            float* P = SL + sj * 12 * NX_;
            #pragma unroll
            for (int k = 0; k < 5; ++k) cst(P + 9 * NX_ + 64 * k + lane, syy[k]);
            asm volatile("s_waitcnt vmcnt(0)" ::: "memory");
            cstu(&FL[sj * 16 + 6], ut + 1u);
        } else if (w == 7 && hasT) {
            float* P = SL + sj * 12 * NX_;
            #pragma unroll
            for (int k = 0; k < 5; ++k) { int c = 64 * k + lane;
                cst(P + 10 * NX_ + c, syy[k]); cst(P + 11 * NX_ + c, sxy[k]); }
            asm volatile("s_waitcnt vmcnt(0)" ::: "memory");
            cstu(&FL[sj * 16 + 7], ut + 1u);
        }
    }

    // ---------- final output: out[s][r][t] = 0.5*(rec[t] + rec[t+1]) ----------
    for (int i = 0; i < nrec; ++i) {
        const float* rp = recbase + (s * NREC_ + recid[i]) * NT_;
        float* op = out + (s * NREC_ + recid[i]) * (NT_ - 1);
        for (int t = 0; t < NT_ - 1; ++t) op[t] = 0.5f * (rp[t] + rp[t + 1]);
    }
}

extern "C" void kernel_launch(void* const* d_in, const int* in_sizes, int n_in,
                              void* d_out, int out_size, void* d_ws, size_t ws_size,
                              hipStream_t stream)
{
    const float* lamb = (const float*)d_in[0];
    const float* mu   = (const float*)d_in[1];
    const float* buoy = (const float*)d_in[2];
    const float* amps = (const float*)d_in[3];
    const int*   src  = (const int*)d_in[4];
    const int*   recl = (const int*)d_in[5];
    float* out = (float*)d_out;
    float* ws  = (float*)d_ws;

    init_kernel<<<dim3(512), dim3(256), 0, stream>>>(ws);
    elastic_kernel<<<dim3(NBLK_), dim3(512), 0, stream>>>(lamb, mu, buoy, amps, src, recl, out, ws);
}

// Round 12
// 1568.943 us; speedup vs baseline: 2.8629x; 2.8629x over previous
//
#include <hip/hip_runtime.h>
#include <math.h>

constexpr int NY_ = 320, NX_ = 320, NT_ = 160, SHOTS_ = 2, NSRC_ = 8, NREC_ = 96;
constexpr float DT_  = 4.0e-4f;
constexpr float C1_  = 9.0f / 8.0f;
constexpr float C2_  = -1.0f / 24.0f;
constexpr float IDH_ = 0.25f;           // 1/DH, exact
constexpr int NP_     = NY_ * NX_;
constexpr int NSTRIP_ = 40;             // 8-row strips per shot
constexpr int NBLK_   = SHOTS_ * NSTRIP_;
constexpr int REC_OFF_ = 8 * NP_;                          // mirrors gVy,gVx,gSyy,gSxy x 2 shots
constexpr int FLG_OFF_ = REC_OFF_ + SHOTS_ * NREC_ * NT_;
constexpr int WS_WORDS_ = FLG_OFF_ + 16 * NBLK_ + 64;
// Flags FL[sj*16+i]: 0=VB0(vy,vx r0) 1=VB1(vy r0+1) 2=VT6(vx r0+6) 3=VT7(vy,vx r0+7)
//                    4=SB0(syy,sxy r0) 5=SB1(sxy r0+1) 6=ST6(syy r0+6) 7=ST7(syy,sxy r0+7)

// ---- all cross-block traffic: agent-scope relaxed atomics -> sc0 sc1 (IF).
// Verified r3-r9; the r10 same-XCD plain-store path deadlocked — single path only.
__device__ __forceinline__ float cld(const float* p) {
    return __hip_atomic_load(p, __ATOMIC_RELAXED, __HIP_MEMORY_SCOPE_AGENT);
}
__device__ __forceinline__ void cst(float* p, float v) {
    __hip_atomic_store(p, v, __ATOMIC_RELAXED, __HIP_MEMORY_SCOPE_AGENT);
}
__device__ __forceinline__ unsigned cldu(const unsigned* p) {
    return __hip_atomic_load(p, __ATOMIC_RELAXED, __HIP_MEMORY_SCOPE_AGENT);
}
__device__ __forceinline__ void cstu(unsigned* p, unsigned v) {
    __hip_atomic_store(p, v, __ATOMIC_RELAXED, __HIP_MEMORY_SCOPE_AGENT);
}
__device__ __forceinline__ void gpoll2(const unsigned* a, const unsigned* b, unsigned tgt) {
    while (cldu(a) < tgt || cldu(b) < tgt) __builtin_amdgcn_s_sleep(1);
    asm volatile("" ::: "memory");
}
// guarded LDS x-tap (r5-r9 verified)
__device__ __forceinline__ float ltap(const float (*A)[NX_], int ly, int c) {
    return ((unsigned)c < (unsigned)NX_) ? A[ly][c] : 0.0f;
}
// register x-tap via wave shuffle (r5-r9 verified)
__device__ __forceinline__ float shtap(float cur, float adj, int lane, int dx) {
    int idx = (lane + dx) & 63;
    float a = __shfl(cur, idx, 64);
    float b = __shfl(adj, idx, 64);
    return ((unsigned)(lane + dx) < 64u) ? a : b;
}

__global__ void init_kernel(float* __restrict__ ws) {
    for (int i = blockIdx.x * 256 + threadIdx.x; i < WS_WORDS_; i += gridDim.x * 256)
        ws[i] = 0.0f;
}

__global__ __launch_bounds__(512, 2)
void elastic_kernel(const float* __restrict__ lamb, const float* __restrict__ mu,
                    const float* __restrict__ buoy, const float* __restrict__ amps,
                    const int* __restrict__ src_loc, const int* __restrict__ rec_loc,
                    float* __restrict__ out, float* __restrict__ ws)
{
    // r6-verified LDS layout: row index = gy - r0 + 2; halos {0,1,10,11}, own 2..9.
    __shared__ float Lsyy[12][NX_], Lsxy[12][NX_], Lvy[12][NX_], Lvx[12][NX_];

    const int tid = threadIdx.x, lane = tid & 63, w = tid >> 6;   // wave = row
    const int bid = blockIdx.x, s = bid / NSTRIP_, j = bid % NSTRIP_;
    const int r0 = j * 8, gy = r0 + w, yi = w + 2, sj = bid;
    const bool hasB = (j > 0), hasT = (j < NSTRIP_ - 1);

    float* gVy  = ws + (0 * SHOTS_ + s) * NP_;
    float* gVx  = ws + (1 * SHOTS_ + s) * NP_;
    float* gSyy = ws + (2 * SHOTS_ + s) * NP_;
    float* gSxy = ws + (3 * SHOTS_ + s) * NP_;
    unsigned* FL = (unsigned*)(ws + FLG_OFF_);
    float* recbase = ws + REC_OFF_;

    // --- loop invariants (double PML; formulas verbatim r6, absmax 2.5e-29) ---
    const double d0 = 3.0 * 1600.0 * log(1000.0) / (2.0 * 20.0 * 4.0);
    double py = 0.0;
    if (gy < 20)             { double u = (20.0 - gy) / 20.0;           py = u * u; }
    else if (gy >= NY_ - 20) { double u = (gy - (NY_ - 1 - 20)) / 20.0; py = u * u; }
    const float by = (float)exp(-d0 * py * 4.0e-4);
    const float bym1 = by - 1.0f;

    float bx[5], bxm1[5], mk[5], la[5], muv[5], bu[5], l2m[5];
    #pragma unroll
    for (int k = 0; k < 5; ++k) {
        int c = 64 * k + lane;
        double px = 0.0;
        if (c < 20)             { double u = (20.0 - c) / 20.0;           px = u * u; }
        else if (c >= NX_ - 20) { double u = (c - (NX_ - 1 - 20)) / 20.0; px = u * u; }
        bx[k] = (float)exp(-d0 * px * 4.0e-4);
        bxm1[k] = bx[k] - 1.0f;
        mk[k] = (gy < 2 || gy >= NY_ - 2 || c < 2 || c >= NX_ - 2) ? 0.0f : 1.0f;
        la[k]  = lamb[gy * NX_ + c];
        muv[k] = mu[gy * NX_ + c];
        bu[k]  = buoy[gy * NX_ + c];
        l2m[k] = la[k] + 2.0f * muv[k];
    }
    unsigned long long sm = 0ull;
    for (int js = 0; js < NSRC_; ++js) {
        int sy = src_loc[(s * NSRC_ + js) * 2 + 0];
        int sxc = src_loc[(s * NSRC_ + js) * 2 + 1];
        if (sy == gy && (sxc & 63) == lane) sm |= 1ull << (8 * (sxc >> 6) + js);
    }
    // receiver ownership: owning thread records its own register (r11-verified)
    int nrec = 0, recid[8], reck[8];
    for (int r = 0; r < NREC_; ++r) {
        int ry = rec_loc[(s * NREC_ + r) * 2 + 0];
        int rx = rec_loc[(s * NREC_ + r) * 2 + 1];
        if (ry == gy && (rx & 63) == lane && nrec < 8) { recid[nrec] = r; reck[nrec] = rx >> 6; ++nrec; }
    }

    for (int i = tid; i < 12 * NX_; i += 512) {
        ((float*)Lsyy)[i] = 0.f; ((float*)Lsxy)[i] = 0.f;
        ((float*)Lvy)[i]  = 0.f; ((float*)Lvx)[i]  = 0.f;
    }
    __syncthreads();

    float vy[5] = {}, vx[5] = {}, syy[5] = {}, sxy[5] = {}, sxx[5] = {};
    float msyyy[5] = {}, msxyy[5] = {}, msxyx[5] = {}, msxxx[5] = {};
    float mvyy[5] = {}, mvyx[5] = {}, mvxy[5] = {}, mvxx[5] = {};

    for (int t = 0; t < NT_; ++t) {
        const unsigned ut = (unsigned)t;

        // ================= VELOCITY(t) =================
        __syncthreads();   // arrival: prior stress LDS writes complete
        if (w == 0 && hasB) {        // bottom stress halo: poll + import (one wave)
            gpoll2(&FL[(sj - 1) * 16 + 6], &FL[(sj - 1) * 16 + 7], ut);
            #pragma unroll
            for (int k = 0; k < 5; ++k) {
                int c = 64 * k + lane;
                float a0 = cld(gSyy + (r0 - 2) * NX_ + c);
                float a1 = cld(gSyy + (r0 - 1) * NX_ + c);
                float b1 = cld(gSxy + (r0 - 1) * NX_ + c);
                Lsyy[0][c] = a0; Lsyy[1][c] = a1; Lsxy[1][c] = b1;
            }
        } else if (w == 7 && hasT) { // top stress halo
            gpoll2(&FL[(sj + 1) * 16 + 4], &FL[(sj + 1) * 16 + 5], ut);
            #pragma unroll
            for (int k = 0; k < 5; ++k) {
                int c = 64 * k + lane;
                float a2 = cld(gSyy + (r0 + 8) * NX_ + c);
                float b2 = cld(gSxy + (r0 + 8) * NX_ + c);
                float b3 = cld(gSxy + (r0 + 9) * NX_ + c);
                Lsyy[10][c] = a2; Lsxy[10][c] = b2; Lsxy[11][c] = b3;
            }
        }
        __syncthreads();   // halos visible

        #pragma unroll
        for (int k = 0; k < 5; ++k) {   // r6-verified velocity body
            const int c = 64 * k + lane;
            const float sxxP = (k < 4) ? sxx[k + 1] : 0.0f;
            const float sxxM = (k > 0) ? sxx[k - 1] : 0.0f;
            float d, ay, ax;
            d = (C1_ * (syy[k] - Lsyy[yi - 1][c]) + C2_ * (Lsyy[yi + 1][c] - Lsyy[yi - 2][c])) * IDH_;
            msyyy[k] = by * msyyy[k] + bym1 * d;
            ay = d + msyyy[k];
            d = (C1_ * (ltap(Lsxy, yi, c + 1) - sxy[k])
               + C2_ * (ltap(Lsxy, yi, c + 2) - ltap(Lsxy, yi, c - 1))) * IDH_;
            msxyx[k] = bx[k] * msxyx[k] + bxm1[k] * d;
            ay = ay + d + msxyx[k];
            vy[k] = vy[k] + DT_ * bu[k] * ay;
            d = (C1_ * (sxx[k] - shtap(sxx[k], sxxM, lane, -1))
               + C2_ * (shtap(sxx[k], sxxP, lane, 1) - shtap(sxx[k], sxxM, lane, -2))) * IDH_;
            msxxx[k] = bx[k] * msxxx[k] + bxm1[k] * d;
            ax = d + msxxx[k];
            d = (C1_ * (Lsxy[yi + 1][c] - sxy[k]) + C2_ * (Lsxy[yi + 2][c] - Lsxy[yi - 1][c])) * IDH_;
            msxyy[k] = by * msxyy[k] + bym1 * d;
            ax = ax + d + msxyy[k];
            vx[k] = vx[k] + DT_ * bu[k] * ax;
            unsigned m = (unsigned)(sm >> (8 * k)) & 0xFFu;
            if (m) {
                for (int js = 0; js < NSRC_; ++js)
                    if (m & (1u << js)) vy[k] += DT_ * amps[(s * NSRC_ + js) * NT_ + t] * bu[k];
            }
            vy[k] *= mk[k]; vx[k] *= mk[k];
            Lvy[yi][c] = vy[k]; Lvx[yi][c] = vx[k];
        }
        for (int i = 0; i < nrec; ++i)
            recbase[(s * NREC_ + recid[i]) * NT_ + t] = vy[reck[i]];

        // owner-wave register publish + per-row flag (early flag posting)
        if (w == 0 && hasB) {
            #pragma unroll
            for (int k = 0; k < 5; ++k) { int c = 64 * k + lane;
                cst(gVy + r0 * NX_ + c, vy[k]); cst(gVx + r0 * NX_ + c, vx[k]); }
            asm volatile("s_waitcnt vmcnt(0)" ::: "memory");
            cstu(&FL[sj * 16 + 0], ut + 1u);
        } else if (w == 1 && hasB) {
            #pragma unroll
            for (int k = 0; k < 5; ++k) cst(gVy + (r0 + 1) * NX_ + 64 * k + lane, vy[k]);
            asm volatile("s_waitcnt vmcnt(0)" ::: "memory");
            cstu(&FL[sj * 16 + 1], ut + 1u);
        } else if (w == 6 && hasT) {
            #pragma unroll
            for (int k = 0; k < 5; ++k) cst(gVx + (r0 + 6) * NX_ + 64 * k + lane, vx[k]);
            asm volatile("s_waitcnt vmcnt(0)" ::: "memory");
            cstu(&FL[sj * 16 + 2], ut + 1u);
        } else if (w == 7 && hasT) {
            #pragma unroll
            for (int k = 0; k < 5; ++k) { int c = 64 * k + lane;
                cst(gVy + (r0 + 7) * NX_ + c, vy[k]); cst(gVx + (r0 + 7) * NX_ + c, vx[k]); }
            asm volatile("s_waitcnt vmcnt(0)" ::: "memory");
            cstu(&FL[sj * 16 + 3], ut + 1u);
        }

        // ================= STRESS(t) =================
        __syncthreads();   // arrival: velocity LDS writes complete
        if (w == 0 && hasB) {        // bottom velocity halo
            gpoll2(&FL[(sj - 1) * 16 + 2], &FL[(sj - 1) * 16 + 3], ut + 1u);
            #pragma unroll
            for (int k = 0; k < 5; ++k) {
                int c = 64 * k + lane;
                float a0 = cld(gVy + (r0 - 1) * NX_ + c);
                float b0 = cld(gVx + (r0 - 2) * NX_ + c);
                float b1 = cld(gVx + (r0 - 1) * NX_ + c);
                Lvy[1][c] = a0; Lvx[0][c] = b0; Lvx[1][c] = b1;
            }
        } else if (w == 7 && hasT) { // top velocity halo
            gpoll2(&FL[(sj + 1) * 16 + 0], &FL[(sj + 1) * 16 + 1], ut + 1u);
            #pragma unroll
            for (int k = 0; k < 5; ++k) {
                int c = 64 * k + lane;
                float a1 = cld(gVy + (r0 + 8) * NX_ + c);
                float a2 = cld(gVy + (r0 + 9) * NX_ + c);
                float b2 = cld(gVx + (r0 + 8) * NX_ + c);
                Lvy[10][c] = a1; Lvy[11][c] = a2; Lvx[10][c] = b2;
            }
        }
        __syncthreads();

        #pragma unroll
        for (int k = 0; k < 5; ++k) {   // r6-verified stress body
            const int c = 64 * k + lane;
            float d, e1, e2, g;
            d = (C1_ * (Lvy[yi + 1][c] - vy[k]) + C2_ * (Lvy[yi + 2][c] - Lvy[yi - 1][c])) * IDH_;
            mvyy[k] = by * mvyy[k] + bym1 * d;
            e1 = d + mvyy[k];
            d = (C1_ * (vx[k] - ltap(Lvx, yi, c - 1))
               + C2_ * (ltap(Lvx, yi, c + 1) - ltap(Lvx, yi, c - 2))) * IDH_;
            mvxx[k] = bx[k] * mvxx[k] + bxm1[k] * d;
            e2 = d + mvxx[k];
            syy[k] = (syy[k] + DT_ * (l2m[k] * e1 + la[k] * e2)) * mk[k];
            sxx[k] = (sxx[k] + DT_ * (l2m[k] * e2 + la[k] * e1)) * mk[k];
            d = (C1_ * (ltap(Lvy, yi, c + 1) - vy[k])
               + C2_ * (ltap(Lvy, yi, c + 2) - ltap(Lvy, yi, c - 1))) * IDH_;
            mvyx[k] = bx[k] * mvyx[k] + bxm1[k] * d;
            g = d + mvyx[k];
            d = (C1_ * (vx[k] - Lvx[yi - 1][c]) + C2_ * (Lvx[yi + 1][c] - Lvx[yi - 2][c])) * IDH_;
            mvxy[k] = by * mvxy[k] + bym1 * d;
            g = g + d + mvxy[k];
            sxy[k] = (sxy[k] + DT_ * muv[k] * g) * mk[k];
            Lsyy[yi][c] = syy[k]; Lsxy[yi][c] = sxy[k];
        }

        if (w == 0 && hasB) {
            #pragma unroll
            for (int k = 0; k < 5; ++k) { int c = 64 * k + lane;
                cst(gSyy + r0 * NX_ + c, syy[k]); cst(gSxy + r0 * NX_ + c, sxy[k]); }
            asm volatile("s_waitcnt vmcnt(0)" ::: "memory");
            cstu(&FL[sj * 16 + 4], ut + 1u);
        } else if (w == 1 && hasB) {
            #pragma unroll
            for (int k = 0; k < 5; ++k) cst(gSxy + (r0 + 1) * NX_ + 64 * k + lane, sxy[k]);
            asm volatile("s_waitcnt vmcnt(0)" ::: "memory");
            cstu(&FL[sj * 16 + 5], ut + 1u);
        } else if (w == 6 && hasT) {
            #pragma unroll
            for (int k = 0; k < 5; ++k) cst(gSyy + (r0 + 6) * NX_ + 64 * k + lane, syy[k]);
            asm volatile("s_waitcnt vmcnt(0)" ::: "memory");
            cstu(&FL[sj * 16 + 6], ut + 1u);
        } else if (w == 7 && hasT) {
            #pragma unroll
            for (int k = 0; k < 5; ++k) { int c = 64 * k + lane;
                cst(gSyy + (r0 + 7) * NX_ + c, syy[k]); cst(gSxy + (r0 + 7) * NX_ + c, sxy[k]); }
            asm volatile("s_waitcnt vmcnt(0)" ::: "memory");
            cstu(&FL[sj * 16 + 7], ut + 1u);
        }
    }

    // ---------- final output: out[s][r][t] = 0.5*(rec[t] + rec[t+1]) ----------
    for (int i = 0; i < nrec; ++i) {
        const float* rp = recbase + (s * NREC_ + recid[i]) * NT_;
        float* op = out + (s * NREC_ + recid[i]) * (NT_ - 1);
        for (int t = 0; t < NT_ - 1; ++t) op[t] = 0.5f * (rp[t] + rp[t + 1]);
    }
}

extern "C" void kernel_launch(void* const* d_in, const int* in_sizes, int n_in,
                              void* d_out, int out_size, void* d_ws, size_t ws_size,
                              hipStream_t stream)
{
    const float* lamb = (const float*)d_in[0];
    const float* mu   = (const float*)d_in[1];
    const float* buoy = (const float*)d_in[2];
    const float* amps = (const float*)d_in[3];
    const int*   src  = (const int*)d_in[4];
    const int*   recl = (const int*)d_in[5];
    float* out = (float*)d_out;
    float* ws  = (float*)d_ws;

    init_kernel<<<dim3(512), dim3(256), 0, stream>>>(ws);
    elastic_kernel<<<dim3(NBLK_), dim3(512), 0, stream>>>(lamb, mu, buoy, amps, src, recl, out, ws);
}